// Round 1
// baseline (393.315 us; speedup 1.0000x reference)
//
#include <hip/hip_runtime.h>
#include <hip/hip_bf16.h>
#include <stdint.h>

// Problem constants (from reference)
#define IN_F   1024
#define OUT_F  1024
#define NLEAF  16
#define BATCH  4096

// GEMM restructure: k = i*16 + l, K padded 16384 -> 16416 (last 32 cols:
// 16 bias columns carrying g / pb, then 16 zero columns) so K % (BK*SPLITK) == 0.
#define KP      16416
#define TM      128
#define TN      128
#define BK      32
#define SPLITK  3
#define KITERS  (KP / (BK * SPLITK))   // 171

typedef __bf16 bf16x8 __attribute__((ext_vector_type(8)));
typedef float  f32x4  __attribute__((ext_vector_type(4)));

#define ASYNC_COPY16(gp, lp)                                                         \
  __builtin_amdgcn_global_load_lds((const __attribute__((address_space(1))) void*)(gp), \
                                   (__attribute__((address_space(3))) void*)(lp),       \
                                   16, 0, 0)

// ---------------------------------------------------------------------------
// Kernel 1: gating softmax.  g[b,l] = softmax_l(x[b,:] @ gw[:,l] + gb[l]).
// One wave per batch row; 4 waves (256 threads) per block.
// ---------------------------------------------------------------------------
__global__ __launch_bounds__(256) void gate_kernel(
    const float* __restrict__ x, const float* __restrict__ gw,
    const float* __restrict__ gb, float* __restrict__ g) {
  const int lane = threadIdx.x & 63;
  const int b = blockIdx.x * 4 + (threadIdx.x >> 6);

  float acc[NLEAF];
#pragma unroll
  for (int l = 0; l < NLEAF; ++l) acc[l] = 0.f;

  const float* xrow = x + b * IN_F;
#pragma unroll 4
  for (int tile = 0; tile < IN_F / 64; ++tile) {
    const int i = lane + tile * 64;
    const float xv = xrow[i];             // coalesced across lanes
    const float* gwp = gw + i * NLEAF;    // 64B row, L1/L2 resident (64 KB total)
#pragma unroll
    for (int l = 0; l < NLEAF; ++l) acc[l] += xv * gwp[l];
  }

  // butterfly reduce each of the 16 sums across the wave
#pragma unroll
  for (int l = 0; l < NLEAF; ++l) {
    float v = acc[l];
#pragma unroll
    for (int off = 32; off > 0; off >>= 1) v += __shfl_xor(v, off, 64);
    acc[l] = v;
  }

  // every lane now holds all 16 logits; softmax redundantly, lanes 0..15 write
  float mx = -1e30f;
#pragma unroll
  for (int l = 0; l < NLEAF; ++l) { acc[l] += gb[l]; mx = fmaxf(mx, acc[l]); }
  float s = 0.f;
  float e[NLEAF];
#pragma unroll
  for (int l = 0; l < NLEAF; ++l) { e[l] = __expf(acc[l] - mx); s += e[l]; }
  const float inv = 1.f / s;
  if (lane < NLEAF) g[b * NLEAF + lane] = e[lane] * inv;
}

// ---------------------------------------------------------------------------
// Kernel 2: pack A.  y[b,k] = bf16( x[b, k>>4] * g[b, k&15] )  for k < 16384,
// then 16 bias cols = g[b,l], then 16 zero cols.  8 elems (16 B) per thread.
// ---------------------------------------------------------------------------
__global__ __launch_bounds__(256) void pack_y_kernel(
    const float* __restrict__ x, const float* __restrict__ g,
    __hip_bfloat16* __restrict__ y) {
  const int b = blockIdx.y;
  const int c = blockIdx.x * blockDim.x + threadIdx.x;
  if (c >= KP / 8) return;
  const int k0 = c * 8;

  __align__(16) __hip_bfloat16 tmp[8];
  if (k0 < IN_F * NLEAF) {
    const float xv = x[b * IN_F + (k0 >> 4)];   // one i per 8-chunk (8 | 16)
    const float* gp = g + b * NLEAF + (k0 & 15);
#pragma unroll
    for (int j = 0; j < 8; ++j) tmp[j] = __float2bfloat16(xv * gp[j]);
  } else {
    const int l0 = k0 - IN_F * NLEAF;
#pragma unroll
    for (int j = 0; j < 8; ++j) {
      const int l = l0 + j;
      tmp[j] = __float2bfloat16(l < NLEAF ? g[b * NLEAF + l] : 0.f);
    }
  }
  *(uint4*)(y + (long)b * KP + k0) = *(const uint4*)tmp;
}

// ---------------------------------------------------------------------------
// Kernel 3: pack B^T.  W[o,k] = bf16(pw[o, k>>4, k&15]) = bf16(pw_flat[o*16384+k])
// (pw row-major IS the [OUT,K] matrix), bias cols = pb[o,l], then zeros.
// ---------------------------------------------------------------------------
__global__ __launch_bounds__(256) void pack_w_kernel(
    const float* __restrict__ pw, const float* __restrict__ pb,
    __hip_bfloat16* __restrict__ W) {
  const int o = blockIdx.y;
  const int c = blockIdx.x * blockDim.x + threadIdx.x;
  if (c >= KP / 8) return;
  const int k0 = c * 8;

  __align__(16) __hip_bfloat16 tmp[8];
  if (k0 < IN_F * NLEAF) {
    const float4* p = (const float4*)(pw + (long)o * (IN_F * NLEAF) + k0);
    const float4 v0 = p[0], v1 = p[1];
    tmp[0] = __float2bfloat16(v0.x); tmp[1] = __float2bfloat16(v0.y);
    tmp[2] = __float2bfloat16(v0.z); tmp[3] = __float2bfloat16(v0.w);
    tmp[4] = __float2bfloat16(v1.x); tmp[5] = __float2bfloat16(v1.y);
    tmp[6] = __float2bfloat16(v1.z); tmp[7] = __float2bfloat16(v1.w);
  } else {
    const int l0 = k0 - IN_F * NLEAF;
#pragma unroll
    for (int j = 0; j < 8; ++j) {
      const int l = l0 + j;
      tmp[j] = __float2bfloat16(l < NLEAF ? pb[o * NLEAF + l] : 0.f);
    }
  }
  *(uint4*)(W + (long)o * KP + k0) = *(const uint4*)tmp;
}

// ---------------------------------------------------------------------------
// Kernel 4: bf16 MFMA GEMM, B^T layout (m97 recipe): 128x128 block tile, BK=32,
// global_load_lds width=16 staging, 4 waves each computing a 64x64 sub-tile
// (4x4 grid of 16x16x32 MFMAs).  Split-K=3 with fp32 atomicAdd epilogue.
// ---------------------------------------------------------------------------
__global__ __launch_bounds__(256, 2) void gemm_kernel(
    const __hip_bfloat16* __restrict__ Y,   // [BATCH, KP]
    const __hip_bfloat16* __restrict__ W,   // [OUT_F, KP]
    float* __restrict__ out) {              // [BATCH, OUT_F] (pre-zeroed)
  __shared__ __align__(16) __hip_bfloat16 As[TM * BK];  // 8 KB
  __shared__ __align__(16) __hip_bfloat16 Bs[TN * BK];  // 8 KB

  const int t    = threadIdx.x;
  const int lane = t & 63;
  const int w    = t >> 6;
  const int quad = lane >> 4;
  const int r16  = lane & 15;

  const int m0 = blockIdx.x * TM;
  const int n0 = blockIdx.y * TN;
  const int k0 = blockIdx.z * (KITERS * BK);

  const __hip_bfloat16* aG = Y + (long)m0 * KP + k0;
  const __hip_bfloat16* bG = W + (long)n0 * KP + k0;

  // staging: 8 KB per tile = 512 16-byte chunks; chunk c -> row c>>2, 16B-slot c&3.
  // LDS dest = base + c*16: within a wave, lane l lands at waveuniform + l*16,
  // satisfying global_load_lds's uniform-base + lane*size constraint.
  const int  c0 = t, c1 = t + 256;
  const long aOff0 = (long)(c0 >> 2) * KP + (c0 & 3) * 8;  // elements
  const long aOff1 = (long)(c1 >> 2) * KP + (c1 & 3) * 8;

  const int wm = (w >> 1) * 64;
  const int wn = (w & 1) * 64;

  f32x4 acc[4][4] = {};

  for (int it = 0; it < KITERS; ++it) {
    ASYNC_COPY16(aG + aOff0, (char*)As + c0 * 16);
    ASYNC_COPY16(aG + aOff1, (char*)As + c1 * 16);
    ASYNC_COPY16(bG + aOff0, (char*)Bs + c0 * 16);
    ASYNC_COPY16(bG + aOff1, (char*)Bs + c1 * 16);
    __syncthreads();  // compiler emits vmcnt(0) drain before s_barrier

    bf16x8 af[4], bfr[4];
    // A frag: A[m = r16][k = quad*8 + j] ; B frag symmetric for B^T operand
#pragma unroll
    for (int mi = 0; mi < 4; ++mi)
      af[mi] = *(const bf16x8*)(As + (wm + mi * 16 + r16) * BK + quad * 8);
#pragma unroll
    for (int ni = 0; ni < 4; ++ni)
      bfr[ni] = *(const bf16x8*)(Bs + (wn + ni * 16 + r16) * BK + quad * 8);

#pragma unroll
    for (int mi = 0; mi < 4; ++mi)
#pragma unroll
      for (int ni = 0; ni < 4; ++ni)
        acc[mi][ni] = __builtin_amdgcn_mfma_f32_16x16x32_bf16(
            af[mi], bfr[ni], acc[mi][ni], 0, 0, 0);

    __syncthreads();
    aG += BK;
    bG += BK;
  }

  // Epilogue: C/D layout col = lane&15, row = quad*4 + reg  [learn_hip m89/m91]
#pragma unroll
  for (int mi = 0; mi < 4; ++mi)
#pragma unroll
    for (int ni = 0; ni < 4; ++ni)
#pragma unroll
      for (int r = 0; r < 4; ++r) {
        const int row = m0 + wm + mi * 16 + quad * 4 + r;
        const int col = n0 + wn + ni * 16 + r16;
        atomicAdd(out + (long)row * OUT_F + col, acc[mi][ni][r]);
      }
}

// ---------------------------------------------------------------------------
// Fallback (ws too small for packed buffers): slow but correct fp32 path.
// ---------------------------------------------------------------------------
__global__ __launch_bounds__(256) void fallback_kernel(
    const float* __restrict__ x, const float* __restrict__ pw,
    const float* __restrict__ pb, const float* __restrict__ g,
    float* __restrict__ out) {
  const int b = blockIdx.x;
  __shared__ float xs[IN_F];
  __shared__ float gs[NLEAF];
  const int t = threadIdx.x;
  for (int j = t; j < IN_F; j += 256) xs[j] = x[(long)b * IN_F + j];
  if (t < NLEAF) gs[t] = g[b * NLEAF + t];
  __syncthreads();
  for (int o = t; o < OUT_F; o += 256) {
    const float* pwo = pw + (long)o * (IN_F * NLEAF);
    float acc = 0.f;
    for (int i = 0; i < IN_F; ++i) {
      const float xv = xs[i];
      float wsum = 0.f;
#pragma unroll
      for (int l = 0; l < NLEAF; ++l) wsum += gs[l] * pwo[i * NLEAF + l];
      acc += xv * wsum;
    }
    float bias = 0.f;
#pragma unroll
    for (int l = 0; l < NLEAF; ++l) bias += gs[l] * pb[o * NLEAF + l];
    out[(long)b * OUT_F + o] = acc + bias;
  }
}

extern "C" void kernel_launch(void* const* d_in, const int* in_sizes, int n_in,
                              void* d_out, int out_size, void* d_ws, size_t ws_size,
                              hipStream_t stream) {
  const float* x  = (const float*)d_in[0];  // [4096,1024]
  const float* gw = (const float*)d_in[1];  // [1024,16]
  const float* gb = (const float*)d_in[2];  // [16]
  const float* pw = (const float*)d_in[3];  // [1024,1024,16]
  const float* pb = (const float*)d_in[4];  // [1024,16]
  float* out = (float*)d_out;               // [4096,1024]

  const size_t y_bytes = (size_t)BATCH * KP * sizeof(__hip_bfloat16);  // 134.5 MB
  const size_t w_bytes = (size_t)OUT_F * KP * sizeof(__hip_bfloat16);  //  33.6 MB
  const size_t g_bytes = (size_t)BATCH * NLEAF * sizeof(float);        //  0.26 MB

  if (ws_size >= y_bytes + w_bytes + g_bytes) {
    __hip_bfloat16* y = (__hip_bfloat16*)d_ws;
    __hip_bfloat16* W = (__hip_bfloat16*)((char*)d_ws + y_bytes);
    float*          g = (float*)((char*)d_ws + y_bytes + w_bytes);

    gate_kernel<<<BATCH / 4, 256, 0, stream>>>(x, gw, gb, g);
    pack_y_kernel<<<dim3((KP / 8 + 255) / 256, BATCH), 256, 0, stream>>>(x, g, y);
    pack_w_kernel<<<dim3((KP / 8 + 255) / 256, OUT_F), 256, 0, stream>>>(pw, pb, W);
    hipMemsetAsync(out, 0, (size_t)BATCH * OUT_F * sizeof(float), stream);
    gemm_kernel<<<dim3(BATCH / TM, OUT_F / TN, SPLITK), 256, 0, stream>>>(y, W, out);
  } else {
    float* g = (float*)d_ws;  // needs only 256 KB
    gate_kernel<<<BATCH / 4, 256, 0, stream>>>(x, gw, gb, g);
    fallback_kernel<<<BATCH, 256, 0, stream>>>(x, pw, pb, g, out);
  }
}